// Round 12
// baseline (411.408 us; speedup 1.0000x reference)
//
#include <hip/hip_runtime.h>

// LPKT forward. B=64, S=128, NQ=2000, C=128, K=64, DE=DC=64.
// R12: R11 step core unchanged. pcR + pcY kernels eliminated:
//  - pcT emits Tp (k-permuted), QB (per-question q_matrix bitmasks),
//    Uwsp (permuted, b2/b3 folded); main composes bases off-chain from
//    2-step-ahead Tp prefetches + register-resident U variants.
//  - y-computation folded into main's epilogue (YP readback, L2-hot).

constexpr int BB = 64, SS = 128, CD = 128;
constexpr int HP2 = 72;     // shorts per hsb row (144B)

typedef short bf16x8 __attribute__((ext_vector_type(8)));
typedef float f32x4  __attribute__((ext_vector_type(4)));

// barrier WITHOUT vmcnt drain: orders LDS only, global prefetches stay in flight
#define BAR() asm volatile("s_waitcnt lgkmcnt(0)\ns_barrier" ::: "memory")

__device__ __forceinline__ short f2bf(float x) {
  unsigned u = __builtin_bit_cast(unsigned, x);
  unsigned r = u + 0x7fffu + ((u >> 16) & 1u);
  return (short)(r >> 16);
}
__device__ __forceinline__ unsigned pk2bf(float a, float b) {
  unsigned ua = __builtin_bit_cast(unsigned, a);
  unsigned ub = __builtin_bit_cast(unsigned, b);
  unsigned ra = ua + 0x7fffu + ((ua >> 16) & 1u);
  unsigned rb = ub + 0x7fffu + ((ub >> 16) & 1u);
  return (ra >> 16) | (rb & 0xffff0000u);
}
__device__ __forceinline__ float sigm(float x) {
  return __builtin_amdgcn_rcpf(1.f + __expf(-x));
}
__device__ __forceinline__ void store_bf4(short* p, float a, float b, float c, float d) {
  uint2 v = {pk2bf(a, b), pk2bf(c, d)};
  *(uint2*)p = v;
}
__device__ __forceinline__ float4 f4add(float4 a, float4 b) {
  return make_float4(a.x + b.x, a.y + b.y, a.z + b.z, a.w + b.w);
}
__device__ __forceinline__ float4 f4sel(float4 a, float4 b, int c) {
  return c ? b : a;
}

// ---------------------------------------------------------------------------
// pcT: per-question tables. Tp is k-PERMUTED (pp=(k&15)*4+(k>>4)). QB holds
// the 4 ballot words of qmat[q]. Block 0 writes Uwsp (permuted, b2/b3 folded).
__global__ void pcT(const float* __restrict__ Eq, const float* __restrict__ qmat,
                    const float* __restrict__ W1, const float* __restrict__ W2,
                    const float* __restrict__ W3, const float* __restrict__ Ec,
                    const float* __restrict__ b1, const float* __restrict__ b2,
                    const float* __restrict__ b3,
                    const float* __restrict__ Wdiff, const float* __restrict__ bdiff,
                    const float* __restrict__ Wdisc, const float* __restrict__ bdisc,
                    float* __restrict__ Tp, float* __restrict__ DIFF,
                    float* __restrict__ DISCq, float* __restrict__ Uwsp,
                    unsigned* __restrict__ QB) {
  int q0 = blockIdx.x * 8, tid = threadIdx.x;
  __shared__ float e[8][64], al[8][64];
  for (int i = tid; i < 512; i += 256) e[i >> 6][i & 63] = Eq[(q0 + (i >> 6)) * 64 + (i & 63)];
  __syncthreads();
  for (int i = tid; i < 512; i += 256) {
    int qq = i >> 6, k = i & 63;
    float s = 0.f;
    #pragma unroll 8
    for (int d = 0; d < 64; ++d) s += e[qq][d] * W1[d * 64 + k];
    al[qq][k] = s;
  }
  __syncthreads();
  {
    int m = tid >> 6, k = tid & 63;
    int pp = (k & 15) * 4 + (k >> 4);
    const float* src = (m < 2 ? W2 : W3) + (m & 1) * 64 * 64;
    float acc[8] = {0.f, 0.f, 0.f, 0.f, 0.f, 0.f, 0.f, 0.f};
    for (int j = 0; j < 64; ++j) {
      float w = src[j * 64 + k];
      #pragma unroll
      for (int qq = 0; qq < 8; ++qq) acc[qq] += al[qq][j] * w;
    }
    #pragma unroll
    for (int qq = 0; qq < 8; ++qq) Tp[(q0 + qq) * 256 + m * 64 + pp] = acc[qq];
  }
  if (tid < 128) {
    int c = tid;
    float acc[8] = {0.f, 0.f, 0.f, 0.f, 0.f, 0.f, 0.f, 0.f};
    for (int d = 0; d < 64; ++d) {
      float w = Wdiff[d * 128 + c];
      #pragma unroll
      for (int qq = 0; qq < 8; ++qq) acc[qq] += e[qq][d] * w;
    }
    #pragma unroll
    for (int qq = 0; qq < 8; ++qq)
      DIFF[(q0 + qq) * 128 + c] = qmat[(q0 + qq) * 128 + c] * sigm(acc[qq] + bdiff[c]);
    // ballots: wave w (of the first two) covers c in [64w, 64w+64)
    int w = tid >> 6, lane = tid & 63;
    #pragma unroll
    for (int qq = 0; qq < 8; ++qq) {
      unsigned long long m = __ballot(qmat[(q0 + qq) * 128 + c] > 0.5f);
      if (lane == 0) {
        QB[(q0 + qq) * 4 + w * 2]     = (unsigned)m;
        QB[(q0 + qq) * 4 + w * 2 + 1] = (unsigned)(m >> 32);
      }
    }
  } else if (tid < 136) {
    int qq = tid - 128;
    float s = 0.f;
    for (int d = 0; d < 64; ++d) s += e[qq][d] * Wdisc[d];
    DISCq[q0 + qq] = 5.f * sigm(s + bdisc[0]);
  }
  if (blockIdx.x == 0) {
    __shared__ float alc[2][64];
    if (tid < 128) {
      int cr = tid >> 6, k = tid & 63;
      float s = b1[k];
      for (int d = 0; d < 64; ++d) s += Ec[cr * 64 + d] * W1[(64 + d) * 64 + k];
      alc[cr][k] = s;
    }
    __syncthreads();
    if (tid < 128) {
      int cr = tid >> 6, k = tid & 63;
      int pp = (k & 15) * 4 + (k >> 4);
      float u2a = 0.f, u2b = 0.f, u3a = 0.f, u3b = 0.f;
      for (int j = 0; j < 64; ++j) {
        float a = alc[cr][j];
        u2a += a * W2[j * 64 + k];       u2b += a * W2[(64 + j) * 64 + k];
        u3a += a * W3[j * 64 + k];       u3b += a * W3[(64 + j) * 64 + k];
      }
      Uwsp[(0 + cr) * 64 + pp] = u2a;  Uwsp[(2 + cr) * 64 + pp] = u2b + b2[k];
      Uwsp[(4 + cr) * 64 + pp] = u3a;  Uwsp[(6 + cr) * 64 + pp] = u3b + b3[k];
    }
  }
}

// ---------------------------------------------------------------------------
// Main. grid=64, block=256 (4 waves), ONE barrier/step. R11 step core; base
// composition moved in (off-chain tail compose from 2-ahead Tp prefetches).
// Epilogue computes y from YP (this block's own rows, L2-hot).
__global__ __launch_bounds__(256, 1) __attribute__((amdgpu_waves_per_eu(1, 1)))
void lpkt_main(
    const float* __restrict__ h0,
    const float* __restrict__ W2, const float* __restrict__ W3,
    const float* __restrict__ W4, const float* __restrict__ b4,
    const float* __restrict__ Wab, const float* __restrict__ bab,
    const int* __restrict__ qs, const int* __restrict__ cs,
    const float* __restrict__ Tp, const float* __restrict__ Uwsp,
    const unsigned* __restrict__ QB,
    const float* __restrict__ DIFF, const float* __restrict__ DISCq,
    float* __restrict__ YP, float* __restrict__ out) {
  __shared__ __align__(16) short hsb[CD * HP2];     // bf16 h (wave-private rows)
  __shared__ __align__(16) short lgb[4 * 64];       // per-wave lg slot (wave-local)
  __shared__ __align__(16) short pkb[4 * 64];       // per-wave pk slot (wave-local)
  __shared__ __align__(16) float up[2][4][2][64];   // u2/u3 partials, dbl-buffered
  __shared__ int qsl[SS], csl[SS];

  const int b    = blockIdx.x;
  const int tid  = threadIdx.x;
  const int lane = tid & 63;
  const int wv   = tid >> 6;       // 0..3
  const int col  = lane & 15;
  const int quad = lane >> 4;
  const int bS   = b * SS;
  const f32x4 zz = {0.f, 0.f, 0.f, 0.f};

  const float* W4a = W4;
  const float* W4b = W4 + 64 * 64;
  const float* W2c = W2 + 128 * 64;
  const float* W3c = W3 + 128 * 64;

  // ---- stage qs/cs ----
  if (tid < 128) qsl[tid] = qs[bS + tid];
  else           csl[tid - 128] = cs[bS + tid - 128];

  // ---- persistent register fragments (k_eff perm: ke=(p&3)*16+(p>>2)) ----
  bf16x8 bw4[4][2], bwb[4][2], bw2[4][2], bw3[4][2], bwab[2];
  float b4r[4];
  #pragma unroll
  for (int nb = 0; nb < 4; ++nb) {
    #pragma unroll
    for (int half = 0; half < 2; ++half)
      #pragma unroll
      for (int j = 0; j < 8; ++j) {
        int p  = half * 32 + quad * 8 + j;
        int ke = (p & 3) * 16 + (p >> 2);
        int kk = ke * 64 + nb * 16 + col;
        bw4[nb][half][j] = f2bf(W4a[kk]);
        bwb[nb][half][j] = f2bf(W4b[kk]);
        bw2[nb][half][j] = f2bf(W2c[kk]);
        bw3[nb][half][j] = f2bf(W3c[kk]);
      }
    b4r[nb] = b4[nb * 16 + col];
  }
  #pragma unroll
  for (int half = 0; half < 2; ++half)
    #pragma unroll
    for (int j = 0; j < 8; ++j) {
      int p  = half * 32 + quad * 8 + j;
      int ke = (p & 3) * 16 + (p >> 2);
      bwab[half][j] = (col == 0) ? f2bf(Wab[ke]) : (short)0;
    }

  // ---- U variants in registers (permuted) ----
  float4 rU2a[2], rU2b[2], rU3a[2], rU3b[2];
  #pragma unroll
  for (int cr = 0; cr < 2; ++cr) {
    rU2a[cr] = *(const float4*)&Uwsp[(0 + cr) * 64 + col * 4];
    rU2b[cr] = *(const float4*)&Uwsp[(2 + cr) * 64 + col * 4];
    rU3a[cr] = *(const float4*)&Uwsp[(4 + cr) * 64 + col * 4];
    rU3b[cr] = *(const float4*)&Uwsp[(6 + cr) * 64 + col * 4];
  }

  // ---- h init: fp32 regs + bf16 LDS copy ----
  float h2[2][4][4];
  #pragma unroll
  for (int mt = 0; mt < 2; ++mt)
    #pragma unroll
    for (int reg = 0; reg < 4; ++reg) {
      int c = 32 * wv + 16 * mt + 4 * quad + reg;
      #pragma unroll
      for (int n = 0; n < 4; ++n) h2[mt][reg][n] = h0[c * 64 + n * 16 + col];
      store_bf4(&hsb[c * HP2 + col * 4],
                h2[mt][reg][0], h2[mt][reg][1], h2[mt][reg][2], h2[mt][reg][3]);
    }

  // ---- pre-loop: pk0 -> u-partials(up[1]); acc = G(h0); af(h0) ----
  int q0i = qs[bS], c0i = cs[bS];
  unsigned qe_w = QB[q0i * 4 + wv];
  {
    float pk[4] = {0.f, 0.f, 0.f, 0.f};
    #pragma unroll
    for (int mt = 0; mt < 2; ++mt)
      #pragma unroll
      for (int reg = 0; reg < 4; ++reg) {
        float q = (float)((qe_w >> (16 * mt + 4 * quad + reg)) & 1u);
        #pragma unroll
        for (int n = 0; n < 4; ++n) pk[n] += q * h2[mt][reg][n];
      }
    #pragma unroll
    for (int n = 0; n < 4; ++n) {
      pk[n] += __shfl_xor(pk[n], 16);
      pk[n] += __shfl_xor(pk[n], 32);
    }
    if (quad == 0) store_bf4(&pkb[wv * 64 + col * 4], pk[0], pk[1], pk[2], pk[3]);
  }
  bf16x8 pf0 = *(const bf16x8*)&pkb[wv * 64 + quad * 8];
  bf16x8 pf1 = *(const bf16x8*)&pkb[wv * 64 + 32 + quad * 8];
  {
    float v2[4], v3[4];
    #pragma unroll
    for (int nb = 0; nb < 4; ++nb) {
      f32x4 a2 = __builtin_amdgcn_mfma_f32_16x16x32_bf16(pf0, bw2[nb][0], zz, 0, 0, 0);
      a2 = __builtin_amdgcn_mfma_f32_16x16x32_bf16(pf1, bw2[nb][1], a2, 0, 0, 0);
      f32x4 a3 = __builtin_amdgcn_mfma_f32_16x16x32_bf16(pf0, bw3[nb][0], zz, 0, 0, 0);
      a3 = __builtin_amdgcn_mfma_f32_16x16x32_bf16(pf1, bw3[nb][1], a3, 0, 0, 0);
      v2[nb] = a2[0]; v3[nb] = a3[0];
    }
    if (quad == 0) {
      *(float4*)&up[1][wv][0][col * 4] = make_float4(v2[0], v2[1], v2[2], v2[3]);
      *(float4*)&up[1][wv][1][col * 4] = make_float4(v3[0], v3[1], v3[2], v3[3]);
    }
  }
  bf16x8 af[2][2];
  #pragma unroll
  for (int mt = 0; mt < 2; ++mt) {
    int r = 32 * wv + 16 * mt + col;
    af[mt][0] = *(const bf16x8*)&hsb[r * HP2 + quad * 8];
    af[mt][1] = *(const bf16x8*)&hsb[r * HP2 + 32 + quad * 8];
  }
  f32x4 acc[2][4];
  #pragma unroll
  for (int mt = 0; mt < 2; ++mt)
    #pragma unroll
    for (int nb = 0; nb < 4; ++nb) {
      acc[mt][nb] = __builtin_amdgcn_mfma_f32_16x16x32_bf16(af[mt][0], bw4[nb][0], zz, 0, 0, 0);
      acc[mt][nb] = __builtin_amdgcn_mfma_f32_16x16x32_bf16(af[mt][1], bw4[nb][1], acc[mt][nb], 0, 0, 0);
    }

  // ---- base pipeline: pbF for t=1; rT prefetch for t=2; qbits 2 ahead ----
  float4 pbF2, pbF3;
  {
    float4 t2b = *(const float4*)&Tp[q0i * 256 + 64 + col * 4];
    float4 t3b = *(const float4*)&Tp[q0i * 256 + 192 + col * 4];
    pbF2 = f4add(t2b, f4sel(rU2b[0], rU2b[1], c0i));
    pbF3 = f4add(t3b, f4sel(rU3b[0], rU3b[1], c0i));
  }
  float4 rT2b, rT2a, rT3b, rT3a;
  {
    int q1 = qs[bS + 1];
    rT2b = *(const float4*)&Tp[q1 * 256 + 64 + col * 4];
    rT3b = *(const float4*)&Tp[q1 * 256 + 192 + col * 4];
    rT2a = *(const float4*)&Tp[q0i * 256 + col * 4];
    rT3a = *(const float4*)&Tp[q0i * 256 + 128 + col * 4];
  }
  unsigned qbw[2];
  qbw[1] = QB[qs[bS + 1] * 4 + wv];
  qbw[0] = QB[qs[bS + 2] * 4 + wv];
  BAR();

  for (int t = 1; t < SS; ++t) {
    const int par = t & 1;
    // ===== post-barrier critical chain =====
    float4 u2v = pbF2, u3v = pbF3;
    {
      float4 a0 = *(const float4*)&up[par][0][0][col * 4];
      float4 a1 = *(const float4*)&up[par][1][0][col * 4];
      float4 a2 = *(const float4*)&up[par][2][0][col * 4];
      float4 a3 = *(const float4*)&up[par][3][0][col * 4];
      float4 c0 = *(const float4*)&up[par][0][1][col * 4];
      float4 c1 = *(const float4*)&up[par][1][1][col * 4];
      float4 c2 = *(const float4*)&up[par][2][1][col * 4];
      float4 c3 = *(const float4*)&up[par][3][1][col * 4];
      u2v.x += a0.x + a1.x + a2.x + a3.x;  u3v.x += c0.x + c1.x + c2.x + c3.x;
      u2v.y += a0.y + a1.y + a2.y + a3.y;  u3v.y += c0.y + c1.y + c2.y + c3.y;
      u2v.z += a0.z + a1.z + a2.z + a3.z;  u3v.z += c0.z + c1.z + c2.z + c3.z;
      u2v.w += a0.w + a1.w + a2.w + a3.w;  u3v.w += c0.w + c1.w + c2.w + c3.w;
    }
    float lg[4];
    lg[0] = sigm(u3v.x) * sigm(2.f * u2v.x);
    lg[1] = sigm(u3v.y) * sigm(2.f * u2v.y);
    lg[2] = sigm(u3v.z) * sigm(2.f * u2v.z);
    lg[3] = sigm(u3v.w) * sigm(2.f * u2v.w);
    if (quad == 0) store_bf4(&lgb[wv * 64 + col * 4], lg[0], lg[1], lg[2], lg[3]);
    unsigned qn_w = qbw[par];
    bf16x8 lf0 = *(const bf16x8*)&lgb[wv * 64 + quad * 8];
    bf16x8 lf1 = *(const bf16x8*)&lgb[wv * 64 + 32 + quad * 8];
    float tvv[4];
    #pragma unroll
    for (int nb = 0; nb < 4; ++nb) {
      f32x4 bb = __builtin_amdgcn_mfma_f32_16x16x32_bf16(lf0, bwb[nb][0], zz, 0, 0, 0);
      bb = __builtin_amdgcn_mfma_f32_16x16x32_bf16(lf1, bwb[nb][1], bb, 0, 0, 0);
      tvv[nb] = bb[0] + b4r[nb];
    }
    // gates + h update + hsb writeback
    #pragma unroll
    for (int mt = 0; mt < 2; ++mt)
      #pragma unroll
      for (int reg = 0; reg < 4; ++reg) {
        int c = 32 * wv + 16 * mt + 4 * quad + reg;
        float qe = (float)((qe_w >> (16 * mt + 4 * quad + reg)) & 1u);
        #pragma unroll
        for (int nb = 0; nb < 4; ++nb) {
          float g = sigm(acc[mt][nb][reg] + tvv[nb]);
          h2[mt][reg][nb] = qe * lg[nb] + g * h2[mt][reg][nb];
        }
        store_bf4(&hsb[c * HP2 + col * 4],
                  h2[mt][reg][0], h2[mt][reg][1], h2[mt][reg][2], h2[mt][reg][3]);
      }
    // pk(t) -> u-partials for step t+1
    {
      float pk[4] = {0.f, 0.f, 0.f, 0.f};
      #pragma unroll
      for (int mt = 0; mt < 2; ++mt)
        #pragma unroll
        for (int reg = 0; reg < 4; ++reg) {
          float q = (float)((qn_w >> (16 * mt + 4 * quad + reg)) & 1u);
          #pragma unroll
          for (int n = 0; n < 4; ++n) pk[n] += q * h2[mt][reg][n];
        }
      #pragma unroll
      for (int n = 0; n < 4; ++n) {
        pk[n] += __shfl_xor(pk[n], 16);
        pk[n] += __shfl_xor(pk[n], 32);
      }
      if (quad == 0) store_bf4(&pkb[wv * 64 + col * 4], pk[0], pk[1], pk[2], pk[3]);
    }
    pf0 = *(const bf16x8*)&pkb[wv * 64 + quad * 8];
    pf1 = *(const bf16x8*)&pkb[wv * 64 + 32 + quad * 8];
    {
      float v2[4], v3[4];
      #pragma unroll
      for (int nb = 0; nb < 4; ++nb) {
        f32x4 a2 = __builtin_amdgcn_mfma_f32_16x16x32_bf16(pf0, bw2[nb][0], zz, 0, 0, 0);
        a2 = __builtin_amdgcn_mfma_f32_16x16x32_bf16(pf1, bw2[nb][1], a2, 0, 0, 0);
        f32x4 a3 = __builtin_amdgcn_mfma_f32_16x16x32_bf16(pf0, bw3[nb][0], zz, 0, 0, 0);
        a3 = __builtin_amdgcn_mfma_f32_16x16x32_bf16(pf1, bw3[nb][1], a3, 0, 0, 0);
        v2[nb] = a2[0]; v3[nb] = a3[0];
      }
      if (quad == 0) {
        *(float4*)&up[par ^ 1][wv][0][col * 4] = make_float4(v2[0], v2[1], v2[2], v2[3]);
        *(float4*)&up[par ^ 1][wv][1][col * 4] = make_float4(v3[0], v3[1], v3[2], v3[3]);
      }
    }
    // af of fresh h; G for next step; ability -> YP[bS+t]
    #pragma unroll
    for (int mt = 0; mt < 2; ++mt) {
      int r = 32 * wv + 16 * mt + col;
      af[mt][0] = *(const bf16x8*)&hsb[r * HP2 + quad * 8];
      af[mt][1] = *(const bf16x8*)&hsb[r * HP2 + 32 + quad * 8];
    }
    #pragma unroll
    for (int mt = 0; mt < 2; ++mt)
      #pragma unroll
      for (int nb = 0; nb < 4; ++nb) {
        acc[mt][nb] = __builtin_amdgcn_mfma_f32_16x16x32_bf16(af[mt][0], bw4[nb][0], zz, 0, 0, 0);
        acc[mt][nb] = __builtin_amdgcn_mfma_f32_16x16x32_bf16(af[mt][1], bw4[nb][1], acc[mt][nb], 0, 0, 0);
      }
    #pragma unroll
    for (int mt = 0; mt < 2; ++mt) {
      f32x4 ya = __builtin_amdgcn_mfma_f32_16x16x32_bf16(af[mt][0], bwab[0], zz, 0, 0, 0);
      ya = __builtin_amdgcn_mfma_f32_16x16x32_bf16(af[mt][1], bwab[1], ya, 0, 0, 0);
      if (col == 0)
        *(float4*)&YP[((size_t)bS + t) * 128 + 32 * wv + 16 * mt + 4 * quad]
            = make_float4(ya[0], ya[1], ya[2], ya[3]);
    }
    // ---- off-chain tail: compose pbF for t+1; reissue rT for t+2 ----
    if (t < SS - 1) {
      int cc1 = csl[t], cc2 = csl[t - 1];
      pbF2 = f4add(f4add(rT2b, rT2a),
                   f4add(f4sel(rU2b[0], rU2b[1], cc1), f4sel(rU2a[0], rU2a[1], cc2)));
      pbF3 = f4add(f4add(rT3b, rT3a),
                   f4add(f4sel(rU3b[0], rU3b[1], cc1), f4sel(rU3a[0], rU3a[1], cc2)));
      int tn = (t + 2 < SS) ? t + 2 : SS - 1;
      int qq1 = qsl[t + 1], qq2 = qsl[t];
      rT2b = *(const float4*)&Tp[qq1 * 256 + 64 + col * 4];
      rT3b = *(const float4*)&Tp[qq1 * 256 + 192 + col * 4];
      rT2a = *(const float4*)&Tp[qq2 * 256 + col * 4];
      rT3a = *(const float4*)&Tp[qq2 * 256 + 128 + col * 4];
      qbw[par] = QB[qsl[tn] * 4 + wv];
    }
    qe_w = qn_w;
    BAR();
  }

  // ---- epilogue: y from YP (this block's rows; all waves' writes drained) ----
  asm volatile("s_waitcnt vmcnt(0)" ::: "memory");
  __syncthreads();
  const float bab0 = bab[0];
  if (tid == 0) out[bS] = 0.f;
  #pragma unroll 2
  for (int i = 0; i < 32; ++i) {
    int t = wv * 32 + i;
    if (t == 0) continue;
    int qt = qsl[t];
    float yp0 = YP[((size_t)bS + t) * 128 + lane];
    float yp1 = YP[((size_t)bS + t) * 128 + 64 + lane];
    float d0  = DIFF[qt * 128 + lane];
    float d1  = DIFF[qt * 128 + 64 + lane];
    unsigned w0 = QB[qt * 4 + (lane >> 5)];
    unsigned w1 = QB[qt * 4 + 2 + (lane >> 5)];
    float qa = (float)((w0 >> (lane & 31)) & 1u);
    float qb = (float)((w1 >> (lane & 31)) & 1u);
    float v = sigm(yp0 + bab0) * qa - d0 + sigm(yp1 + bab0) * qb - d1;
    v += __shfl_xor(v, 32); v += __shfl_xor(v, 16); v += __shfl_xor(v, 8);
    v += __shfl_xor(v, 4);  v += __shfl_xor(v, 2);  v += __shfl_xor(v, 1);
    if (lane == 0) out[bS + t] = sigm(DISCq[qt] * v);
  }
}

// ---------------------------------------------------------------------------
extern "C" void kernel_launch(void* const* d_in, const int* in_sizes, int n_in,
                              void* d_out, int out_size, void* d_ws, size_t ws_size,
                              hipStream_t stream) {
  const int*   qs    = (const int*)d_in[0];
  const int*   cs    = (const int*)d_in[1];
  const float* qmat  = (const float*)d_in[2];
  const float* Eq    = (const float*)d_in[3];
  const float* Ec    = (const float*)d_in[4];
  const float* h0    = (const float*)d_in[5];
  const float* W1    = (const float*)d_in[6];
  const float* b1    = (const float*)d_in[7];
  const float* W2    = (const float*)d_in[8];
  const float* b2    = (const float*)d_in[9];
  const float* W3    = (const float*)d_in[10];
  const float* b3    = (const float*)d_in[11];
  const float* W4    = (const float*)d_in[12];
  const float* b4    = (const float*)d_in[13];
  const float* Wab   = (const float*)d_in[14];
  const float* bab   = (const float*)d_in[15];
  const float* Wdiff = (const float*)d_in[16];
  const float* bdiff = (const float*)d_in[17];
  const float* Wdisc = (const float*)d_in[18];
  const float* bdisc = (const float*)d_in[19];
  float* out = (float*)d_out;

  float* w = (float*)d_ws;
  float*    Tpb   = w;                        // 2000*256 = 512000
  float*    DIFF  = Tpb + 512000;             // 2000*128 = 256000
  float*    DISCq = DIFF + 256000;            // 2000
  float*    Uwsp  = DISCq + 2000;             // 512
  unsigned* QB    = (unsigned*)(Uwsp + 512);  // 2000*4 = 8000
  float*    YP    = (float*)(QB + 8000);      // 8192*128 = 1048576

  pcT<<<250, 256, 0, stream>>>(Eq, qmat, W1, W2, W3, Ec, b1, b2, b3,
                               Wdiff, bdiff, Wdisc, bdisc,
                               Tpb, DIFF, DISCq, Uwsp, QB);
  lpkt_main<<<BB, 256, 0, stream>>>(h0, W2, W3, W4, b4, Wab, bab, qs, cs,
                                    Tpb, Uwsp, QB, DIFF, DISCq, YP, out);
}